// Round 1
// baseline (10705.791 us; speedup 1.0000x reference)
//
#include <hip/hip_runtime.h>
#include <math.h>

#define IN_C 256
#define NUM_CLASSES 91
#define NUM_ANCHORS 9

// levels: H, W, stride, anchor-row offset
static const int   LVL_H[5]      = {100, 50, 25, 13, 7};
static const int   LVL_W[5]      = {100, 50, 25, 13, 7};
static const int   LVL_STRIDE[5] = {8, 16, 32, 64, 128};
static const long long LVL_OFF[5] = {0, 90000, 112500, 118125, 119646};
static const float LVL_BASE[5]   = {32.f, 64.f, 128.f, 256.f, 512.f};

#define TW_STRIDE (256*256*9)

// ---------------------------------------------------------------------------
// Generic 3x3 conv, C_in=256, pad=1. Block: 16x16 threads.
// Output tile: 16 c_out (ty) x 4 rows x 16 cols (tx). c_in chunked by 16.
// ---------------------------------------------------------------------------
template<bool RELU>
__global__ __launch_bounds__(256) void conv3x3_relu(
    const float* __restrict__ x, const float* __restrict__ w,
    const float* __restrict__ b, float* __restrict__ y,
    int C_out, int H, int W)
{
    __shared__ float xs[16][6][18];    // [cin][row][col] halo tile
    __shared__ float wsm[16][16][9];   // [cout_local][cin][tap]
    const int tx = threadIdx.x, ty = threadIdx.y;
    const int tid = ty * 16 + tx;
    const int w0 = blockIdx.x * 16;
    const int h0 = blockIdx.y * 4;
    const int co0 = blockIdx.z * 16;
    const int HW = H * W;

    float acc[4] = {0.f, 0.f, 0.f, 0.f};

    for (int cb = 0; cb < IN_C; cb += 16) {
        // stage input halo tile
        for (int i = tid; i < 16 * 6 * 18; i += 256) {
            int ci = i / 108; int rem = i % 108;
            int r = rem / 18; int c = rem % 18;
            int gh = h0 + r - 1, gw = w0 + c - 1;
            float v = 0.f;
            if ((unsigned)gh < (unsigned)H && (unsigned)gw < (unsigned)W)
                v = x[(cb + ci) * HW + gh * W + gw];
            xs[ci][r][c] = v;
        }
        // stage weights
        for (int i = tid; i < 16 * 16 * 9; i += 256) {
            int col = i / 144; int rem = i % 144;
            int ci = rem / 9; int tap = rem % 9;
            int co = co0 + col;
            wsm[col][ci][tap] = (co < C_out)
                ? w[((long long)co * IN_C + (cb + ci)) * 9 + tap] : 0.f;
        }
        __syncthreads();

        #pragma unroll
        for (int ci = 0; ci < 16; ++ci) {
            float xv[6][3];
            #pragma unroll
            for (int r = 0; r < 6; ++r)
                #pragma unroll
                for (int c = 0; c < 3; ++c)
                    xv[r][c] = xs[ci][r][tx + c];
            #pragma unroll
            for (int ky = 0; ky < 3; ++ky)
                #pragma unroll
                for (int kx = 0; kx < 3; ++kx) {
                    float wv = wsm[ty][ci][ky * 3 + kx];
                    #pragma unroll
                    for (int r = 0; r < 4; ++r)
                        acc[r] = fmaf(xv[r + ky][kx], wv, acc[r]);
                }
        }
        __syncthreads();
    }

    const int co = co0 + ty;
    const int gw = w0 + tx;
    if (co < C_out && gw < W) {
        float bias = b[co];
        #pragma unroll
        for (int r = 0; r < 4; ++r) {
            int gh = h0 + r;
            if (gh < H) {
                float v = acc[r] + bias;
                if (RELU) v = fmaxf(v, 0.f);
                y[(long long)co * HW + gh * W + gw] = v;
            }
        }
    }
}

// ---------------------------------------------------------------------------
// cls output conv (C_out=819) fused with sigmoid + scatter into d_out
// out element: [(lvl_off + (h*W+w)*9 + a)*95 + k], channel c = a*91 + k
// ---------------------------------------------------------------------------
__global__ __launch_bounds__(256) void conv3x3_cls_out(
    const float* __restrict__ x, const float* __restrict__ w,
    const float* __restrict__ b, float* __restrict__ out,
    int H, int W, long long lvl_off)
{
    __shared__ float xs[16][6][18];
    __shared__ float wsm[16][16][9];
    const int C_out = NUM_ANCHORS * NUM_CLASSES;  // 819
    const int tx = threadIdx.x, ty = threadIdx.y;
    const int tid = ty * 16 + tx;
    const int w0 = blockIdx.x * 16;
    const int h0 = blockIdx.y * 4;
    const int co0 = blockIdx.z * 16;
    const int HW = H * W;

    float acc[4] = {0.f, 0.f, 0.f, 0.f};

    for (int cb = 0; cb < IN_C; cb += 16) {
        for (int i = tid; i < 16 * 6 * 18; i += 256) {
            int ci = i / 108; int rem = i % 108;
            int r = rem / 18; int c = rem % 18;
            int gh = h0 + r - 1, gw = w0 + c - 1;
            float v = 0.f;
            if ((unsigned)gh < (unsigned)H && (unsigned)gw < (unsigned)W)
                v = x[(cb + ci) * HW + gh * W + gw];
            xs[ci][r][c] = v;
        }
        for (int i = tid; i < 16 * 16 * 9; i += 256) {
            int col = i / 144; int rem = i % 144;
            int ci = rem / 9; int tap = rem % 9;
            int co = co0 + col;
            wsm[col][ci][tap] = (co < C_out)
                ? w[((long long)co * IN_C + (cb + ci)) * 9 + tap] : 0.f;
        }
        __syncthreads();

        #pragma unroll
        for (int ci = 0; ci < 16; ++ci) {
            float xv[6][3];
            #pragma unroll
            for (int r = 0; r < 6; ++r)
                #pragma unroll
                for (int c = 0; c < 3; ++c)
                    xv[r][c] = xs[ci][r][tx + c];
            #pragma unroll
            for (int ky = 0; ky < 3; ++ky)
                #pragma unroll
                for (int kx = 0; kx < 3; ++kx) {
                    float wv = wsm[ty][ci][ky * 3 + kx];
                    #pragma unroll
                    for (int r = 0; r < 4; ++r)
                        acc[r] = fmaf(xv[r + ky][kx], wv, acc[r]);
                }
        }
        __syncthreads();
    }

    const int co = co0 + ty;
    const int gw = w0 + tx;
    if (co < C_out && gw < W) {
        float bias = b[co];
        int a = co / NUM_CLASSES;
        int k = co % NUM_CLASSES;
        #pragma unroll
        for (int r = 0; r < 4; ++r) {
            int gh = h0 + r;
            if (gh < H) {
                float v = acc[r] + bias;
                float s = 1.f / (1.f + expf(-v));
                long long row = lvl_off + (long long)(gh * W + gw) * 9 + a;
                out[row * 95 + k] = s;
            }
        }
    }
}

// ---------------------------------------------------------------------------
// box decode: read raw reg conv output [36][H][W], compute anchors in closed
// form, write 4 box coords per anchor into d_out[..., 91:95]
// ---------------------------------------------------------------------------
__global__ void decode_boxes(const float* __restrict__ yr, float* __restrict__ out,
                             int H, int W, int stride, float base_size,
                             long long lvl_off)
{
    int idx = blockIdx.x * 256 + threadIdx.x;
    int total = H * W * NUM_ANCHORS;
    if (idx >= total) return;
    int p = idx / 9, a = idx % 9;
    int h = p / W, wc = p % W;
    int HW = H * W;

    float dx = yr[(a * 4 + 0) * HW + p];
    float dy = yr[(a * 4 + 1) * HW + p];
    float dw = yr[(a * 4 + 2) * HW + p];
    float dh = yr[(a * 4 + 3) * HW + p];

    const float scales[3] = {1.f, 1.2599210498948732f, 1.5874010519681994f};
    const float hr[3] = {0.70710678118654752f, 1.f, 1.41421356237309505f};
    int ri = a / 3, si = a % 3;
    float sz = base_size * scales[si];
    float ah = hr[ri] * sz;        // hs
    float aw = sz / hr[ri];        // ws = (1/h_ratio)*size
    float acx = (float)wc * (float)stride;
    float acy = (float)h * (float)stride;

    const float CLAMP = 4.135166556742356f;   // log(1000/16)
    dw = fminf(dw, CLAMP);
    dh = fminf(dh, CLAMP);
    float pcx = dx * aw + acx;
    float pcy = dy * ah + acy;
    float pw = expf(dw) * aw;
    float ph = expf(dh) * ah;

    float* o = out + (lvl_off + (long long)p * 9 + a) * 95 + 91;
    o[0] = pcx - 0.5f * pw;
    o[1] = pcy - 0.5f * ph;
    o[2] = pcx + 0.5f * pw;
    o[3] = pcy + 0.5f * ph;
}

// ---------------------------------------------------------------------------
extern "C" void kernel_launch(void* const* d_in, const int* in_sizes, int n_in,
                              void* d_out, int out_size, void* d_ws, size_t ws_size,
                              hipStream_t stream)
{
    const float* feats[5];
    for (int i = 0; i < 5; ++i) feats[i] = (const float*)d_in[i];
    const float* cls_tw = (const float*)d_in[5];
    const float* cls_tb = (const float*)d_in[6];
    const float* cls_ow = (const float*)d_in[7];
    const float* cls_ob = (const float*)d_in[8];
    const float* reg_tw = (const float*)d_in[9];
    const float* reg_tb = (const float*)d_in[10];
    const float* reg_ow = (const float*)d_in[11];
    const float* reg_ob = (const float*)d_in[12];
    float* out = (float*)d_out;

    char* wsb = (char*)d_ws;
    float* ws0 = (float*)(wsb);                     // 256*100*100*4 = 10.24 MB
    float* ws1 = (float*)(wsb + 10240000);          // 10.24 MB
    float* ws2 = (float*)(wsb + 20480000);          // reg raw out, 1.44 MB max

    dim3 blk(16, 16, 1);

    for (int lvl = 0; lvl < 5; ++lvl) {
        const int H = LVL_H[lvl], W = LVL_W[lvl];
        const int stride = LVL_STRIDE[lvl];
        const long long off = LVL_OFF[lvl];
        dim3 gt((W + 15) / 16, (H + 3) / 4, IN_C / 16);
        dim3 gcls((W + 15) / 16, (H + 3) / 4, (NUM_ANCHORS * NUM_CLASSES + 15) / 16);
        dim3 greg((W + 15) / 16, (H + 3) / 4, (NUM_ANCHORS * 4 + 15) / 16);

        // ---- cls head ----
        conv3x3_relu<true><<<gt, blk, 0, stream>>>(feats[lvl], cls_tw + 0 * TW_STRIDE, cls_tb + 0,   ws0, 256, H, W);
        conv3x3_relu<true><<<gt, blk, 0, stream>>>(ws0,        cls_tw + 1 * TW_STRIDE, cls_tb + 256, ws1, 256, H, W);
        conv3x3_relu<true><<<gt, blk, 0, stream>>>(ws1,        cls_tw + 2 * TW_STRIDE, cls_tb + 512, ws0, 256, H, W);
        conv3x3_relu<true><<<gt, blk, 0, stream>>>(ws0,        cls_tw + 3 * TW_STRIDE, cls_tb + 768, ws1, 256, H, W);
        conv3x3_cls_out<<<gcls, blk, 0, stream>>>(ws1, cls_ow, cls_ob, out, H, W, off);

        // ---- reg head ----
        conv3x3_relu<true><<<gt, blk, 0, stream>>>(feats[lvl], reg_tw + 0 * TW_STRIDE, reg_tb + 0,   ws0, 256, H, W);
        conv3x3_relu<true><<<gt, blk, 0, stream>>>(ws0,        reg_tw + 1 * TW_STRIDE, reg_tb + 256, ws1, 256, H, W);
        conv3x3_relu<true><<<gt, blk, 0, stream>>>(ws1,        reg_tw + 2 * TW_STRIDE, reg_tb + 512, ws0, 256, H, W);
        conv3x3_relu<true><<<gt, blk, 0, stream>>>(ws0,        reg_tw + 3 * TW_STRIDE, reg_tb + 768, ws1, 256, H, W);
        conv3x3_relu<false><<<greg, blk, 0, stream>>>(ws1, reg_ow, reg_ob, ws2, 36, H, W);

        int total = H * W * NUM_ANCHORS;
        decode_boxes<<<(total + 255) / 256, 256, 0, stream>>>(
            ws2, out, H, W, stride, LVL_BASE[lvl], off);
    }
}

// Round 2
// 685.016 us; speedup vs baseline: 15.6285x; 15.6285x over previous
//
#include <hip/hip_runtime.h>
#include <math.h>

typedef unsigned short u16;
typedef __attribute__((ext_vector_type(8))) short s8v;   // 8 x bf16 (4 VGPRs)
typedef __attribute__((ext_vector_type(4))) float f4v;   // MFMA accumulator

#define NUM_CLASSES 91
#define NUM_ANCHORS 9
#define NPB 107            // total 128-pixel blocks across 5 levels
#define TW_STRIDE (256*256*9)

struct Tab {
    int pbs[5];   // starting pixel-block index per level
    int H[5], W[5], HW[5], GP0[5];
};

__device__ __forceinline__ u16 f2bf(float f) {
    unsigned u = __float_as_uint(f);
    u += 0x7fffu + ((u >> 16) & 1u);
    return (u16)(u >> 16);
}

// ---------------------------------------------------------------------------
// fp32 NCHW -> bf16 [pixel][256] (channel-last), per level
// ---------------------------------------------------------------------------
__global__ __launch_bounds__(256) void conv2bf(const float* __restrict__ x,
                                               u16* __restrict__ out,
                                               int HW, int gp0)
{
    int p = blockIdx.x * 64 + (threadIdx.x & 63);
    int cg = threadIdx.x >> 6;              // 0..3
    if (p >= HW) return;
    #pragma unroll
    for (int pass = 0; pass < 8; ++pass) {
        int c0 = pass * 32 + cg * 8;
        s8v v8;
        #pragma unroll
        for (int j = 0; j < 8; ++j)
            v8[j] = (short)f2bf(x[(c0 + j) * HW + p]);
        *(s8v*)(out + (((gp0 + p) << 8) + c0)) = v8;
    }
}

// ---------------------------------------------------------------------------
// Pack conv weights [C_out][256][3][3] fp32 -> bf16 MFMA B-fragment order:
// dst[((chunk*nco16 + co16)*64 + lane)*8 + j], chunk = tap*8 + cib,
// value = W[co16*16 + (lane&15)][cib*32 + (lane>>4)*8 + j][tap]
// ---------------------------------------------------------------------------
__global__ __launch_bounds__(256) void pack_w(const float* __restrict__ w,
                                              u16* __restrict__ dst,
                                              int c_out_real, int nco16)
{
    int idx = blockIdx.x * 256 + threadIdx.x;
    int total = 72 * nco16 * 64;
    if (idx >= total) return;
    int lane = idx & 63;
    int t2 = idx >> 6;
    int co16 = t2 % nco16;
    int chunk = t2 / nco16;
    int tap = chunk >> 3, cib = chunk & 7;
    int co = co16 * 16 + (lane & 15);
    int ci0 = cib * 32 + ((lane >> 4) << 3);
    s8v v8;
    #pragma unroll
    for (int j = 0; j < 8; ++j) {
        float v = (co < c_out_real) ? w[((co << 8) + ci0 + j) * 9 + tap] : 0.f;
        v8[j] = (short)f2bf(v);
    }
    *(s8v*)(dst + (size_t)idx * 8) = v8;
}

// ---------------------------------------------------------------------------
// Implicit-GEMM core: D[64px][64co] per wave, K = 9 taps x 256 ci.
// A from channel-last activations (global), B from packed weights (global).
// ---------------------------------------------------------------------------
__device__ __forceinline__ void gemm_core(
    const u16* __restrict__ act, const u16* __restrict__ wpk,
    int gp0, int p0w, int H, int W, int HW, int nco16, int co16b,
    int lane, f4v acc[4][4])
{
    int pl[4], ph[4], pw_[4];
    bool pv[4];
    #pragma unroll
    for (int s = 0; s < 4; ++s) {
        int p = p0w + s * 16 + (lane & 15);
        pl[s] = p;
        pv[s] = p < HW;
        int pc = pv[s] ? p : 0;
        ph[s] = pc / W;
        pw_[s] = pc % W;
    }
    const int kgrp = (lane >> 4) << 3;
    const s8v zero = {};

    for (int cib = 0; cib < 8; ++cib) {
        #pragma unroll
        for (int tap = 0; tap < 9; ++tap) {
            const int dy = tap / 3 - 1, dx = tap % 3 - 1;
            s8v a[4], b[4];
            #pragma unroll
            for (int s = 0; s < 4; ++s) {
                int hh = ph[s] + dy, ww = pw_[s] + dx;
                bool v = pv[s] && ((unsigned)hh < (unsigned)H) &&
                                  ((unsigned)ww < (unsigned)W);
                int ofs = ((gp0 + pl[s] + dy * W + dx) << 8) + cib * 32 + kgrp;
                s8v ld = *(const s8v*)(act + (v ? ofs : 0));
                a[s] = v ? ld : zero;
            }
            const int chunk = tap * 8 + cib;
            #pragma unroll
            for (int n = 0; n < 4; ++n) {
                int c16 = co16b + n;
                if (c16 >= nco16) c16 = nco16 - 1;   // clamp (padded tiles)
                b[n] = *(const s8v*)(wpk + (((size_t)(chunk * nco16 + c16)) << 9)
                                         + (lane << 3));
            }
            #pragma unroll
            for (int s = 0; s < 4; ++s)
                #pragma unroll
                for (int n = 0; n < 4; ++n)
                    acc[s][n] = __builtin_amdgcn_mfma_f32_16x16x32_bf16(
                        a[s], b[n], acc[s][n], 0, 0, 0);
        }
    }
}

__device__ __forceinline__ int find_lvl_bx(const Tab& t, int bx) {
    int lvl = 0;
    if (bx >= t.pbs[1]) lvl = 1;
    if (bx >= t.pbs[2]) lvl = 2;
    if (bx >= t.pbs[3]) lvl = 3;
    if (bx >= t.pbs[4]) lvl = 4;
    return lvl;
}

// ---------------------------------------------------------------------------
// Tower conv stage: both heads (blockIdx.z), all levels (blockIdx.x),
// C_out=256 (blockIdx.y in {0,1}). ReLU + bf16 channel-last store.
// ---------------------------------------------------------------------------
__global__ __launch_bounds__(256) void conv_tower(
    const u16* __restrict__ inC, u16* __restrict__ outC,
    const u16* __restrict__ inR, u16* __restrict__ outR,
    const u16* __restrict__ wC, const u16* __restrict__ wR,
    const float* __restrict__ bC, const float* __restrict__ bR,
    Tab tab)
{
    const int bx = blockIdx.x;
    const int lvl = find_lvl_bx(tab, bx);
    const int H = tab.H[lvl], W = tab.W[lvl], HW = tab.HW[lvl], gp0 = tab.GP0[lvl];
    const int p0 = (bx - tab.pbs[lvl]) * 128;
    const int head = blockIdx.z;
    const u16* act = head ? inR : inC;
    u16* out = head ? outR : outC;
    const u16* wpk = head ? wR : wC;
    const float* bias = head ? bR : bC;

    const int lane = threadIdx.x & 63, wv = threadIdx.x >> 6;
    const int p0w = p0 + (wv & 1) * 64;
    const int cob = blockIdx.y * 128 + (wv >> 1) * 64;

    f4v acc[4][4];
    #pragma unroll
    for (int s = 0; s < 4; ++s)
        #pragma unroll
        for (int n = 0; n < 4; ++n)
            acc[s][n] = (f4v){0.f, 0.f, 0.f, 0.f};

    gemm_core(act, wpk, gp0, p0w, H, W, HW, 16, cob >> 4, lane, acc);

    #pragma unroll
    for (int n = 0; n < 4; ++n) {
        int co = cob + n * 16 + (lane & 15);
        float bn = bias[co];
        #pragma unroll
        for (int s = 0; s < 4; ++s)
            #pragma unroll
            for (int j = 0; j < 4; ++j) {
                int p = p0w + s * 16 + (lane >> 4) * 4 + j;
                if (p < HW) {
                    float v = acc[s][n][j] + bn;
                    v = fmaxf(v, 0.f);
                    out[((gp0 + p) << 8) + co] = f2bf(v);
                }
            }
    }
}

// ---------------------------------------------------------------------------
// cls output conv: C_out=819 (pad 896), sigmoid + scatter into d_out
// ---------------------------------------------------------------------------
__global__ __launch_bounds__(256) void conv_out_cls(
    const u16* __restrict__ act, const u16* __restrict__ wpk,
    const float* __restrict__ bias, float* __restrict__ dout, Tab tab)
{
    const int bx = blockIdx.x;
    const int lvl = find_lvl_bx(tab, bx);
    const int H = tab.H[lvl], W = tab.W[lvl], HW = tab.HW[lvl], gp0 = tab.GP0[lvl];
    const int p0 = (bx - tab.pbs[lvl]) * 128;
    const int lane = threadIdx.x & 63, wv = threadIdx.x >> 6;
    const int p0w = p0 + (wv & 1) * 64;
    const int cob = blockIdx.y * 128 + (wv >> 1) * 64;

    f4v acc[4][4];
    #pragma unroll
    for (int s = 0; s < 4; ++s)
        #pragma unroll
        for (int n = 0; n < 4; ++n)
            acc[s][n] = (f4v){0.f, 0.f, 0.f, 0.f};

    gemm_core(act, wpk, gp0, p0w, H, W, HW, 52, cob >> 4, lane, acc);

    #pragma unroll
    for (int n = 0; n < 4; ++n) {
        int co = cob + n * 16 + (lane & 15);
        if (co < NUM_ANCHORS * NUM_CLASSES) {
            float bn = bias[co];
            int a = co / NUM_CLASSES;
            int k = co - a * NUM_CLASSES;
            #pragma unroll
            for (int s = 0; s < 4; ++s)
                #pragma unroll
                for (int j = 0; j < 4; ++j) {
                    int p = p0w + s * 16 + (lane >> 4) * 4 + j;
                    if (p < HW) {
                        float v = acc[s][n][j] + bn;
                        float sg = 1.f / (1.f + __expf(-v));
                        dout[((gp0 + p) * 9 + a) * 95 + k] = sg;
                    }
                }
        }
    }
}

// ---------------------------------------------------------------------------
// reg output conv: C_out=36 (pad 48), raw fp32 [pixel][48] store
// ---------------------------------------------------------------------------
__global__ __launch_bounds__(256) void conv_out_reg(
    const u16* __restrict__ act, const u16* __restrict__ wpk,
    const float* __restrict__ bias, float* __restrict__ raw, Tab tab)
{
    const int bx = blockIdx.x;
    const int lvl = find_lvl_bx(tab, bx);
    const int H = tab.H[lvl], W = tab.W[lvl], HW = tab.HW[lvl], gp0 = tab.GP0[lvl];
    const int p0 = (bx - tab.pbs[lvl]) * 128;
    const int lane = threadIdx.x & 63, wv = threadIdx.x >> 6;
    const int p0w = p0 + (wv & 1) * 64;
    const int cob = (wv >> 1) * 64;

    f4v acc[4][4];
    #pragma unroll
    for (int s = 0; s < 4; ++s)
        #pragma unroll
        for (int n = 0; n < 4; ++n)
            acc[s][n] = (f4v){0.f, 0.f, 0.f, 0.f};

    gemm_core(act, wpk, gp0, p0w, H, W, HW, 3, cob >> 4, lane, acc);

    #pragma unroll
    for (int n = 0; n < 4; ++n) {
        int co = cob + n * 16 + (lane & 15);
        if (co < 36) {
            float bn = bias[co];
            #pragma unroll
            for (int s = 0; s < 4; ++s)
                #pragma unroll
                for (int j = 0; j < 4; ++j) {
                    int p = p0w + s * 16 + (lane >> 4) * 4 + j;
                    if (p < HW) raw[(gp0 + p) * 48 + co] = acc[s][n][j] + bn;
                }
        }
    }
}

// ---------------------------------------------------------------------------
// box decode from raw [pixel][48]
// ---------------------------------------------------------------------------
__global__ __launch_bounds__(256) void decode_boxes(
    const float* __restrict__ raw, float* __restrict__ out, Tab tab)
{
    int idx = blockIdx.x * 256 + threadIdx.x;
    if (idx >= 13343 * 9) return;
    int gp = idx / 9, a = idx % 9;
    int lvl = 0;
    if (gp >= tab.GP0[1]) lvl = 1;
    if (gp >= tab.GP0[2]) lvl = 2;
    if (gp >= tab.GP0[3]) lvl = 3;
    if (gp >= tab.GP0[4]) lvl = 4;
    int p = gp - tab.GP0[lvl];
    int W = tab.W[lvl];
    int h = p / W, wc = p % W;
    float stride = (float)(8 << lvl);
    float base = (float)(32 << lvl);

    float dx = raw[gp * 48 + a * 4 + 0];
    float dy = raw[gp * 48 + a * 4 + 1];
    float dw = raw[gp * 48 + a * 4 + 2];
    float dh = raw[gp * 48 + a * 4 + 3];

    const float scales[3] = {1.f, 1.2599210498948732f, 1.5874010519681994f};
    const float hr[3] = {0.70710678118654752f, 1.f, 1.41421356237309505f};
    int ri = a / 3, si = a % 3;
    float sz = base * scales[si];
    float ah = hr[ri] * sz;
    float aw = sz / hr[ri];
    float acx = (float)wc * stride;
    float acy = (float)h * stride;

    const float CLAMP = 4.135166556742356f;
    dw = fminf(dw, CLAMP);
    dh = fminf(dh, CLAMP);
    float pcx = dx * aw + acx;
    float pcy = dy * ah + acy;
    float pw = expf(dw) * aw;
    float ph = expf(dh) * ah;

    float* o = out + ((size_t)gp * 9 + a) * 95 + 91;
    o[0] = pcx - 0.5f * pw;
    o[1] = pcy - 0.5f * ph;
    o[2] = pcx + 0.5f * pw;
    o[3] = pcy + 0.5f * ph;
}

// ---------------------------------------------------------------------------
extern "C" void kernel_launch(void* const* d_in, const int* in_sizes, int n_in,
                              void* d_out, int out_size, void* d_ws, size_t ws_size,
                              hipStream_t stream)
{
    const float* feats[5];
    for (int i = 0; i < 5; ++i) feats[i] = (const float*)d_in[i];
    const float* cls_tw = (const float*)d_in[5];
    const float* cls_tb = (const float*)d_in[6];
    const float* cls_ow = (const float*)d_in[7];
    const float* cls_ob = (const float*)d_in[8];
    const float* reg_tw = (const float*)d_in[9];
    const float* reg_tb = (const float*)d_in[10];
    const float* reg_ow = (const float*)d_in[11];
    const float* reg_ob = (const float*)d_in[12];
    float* out = (float*)d_out;

    static const Tab TAB = {
        {0, 79, 99, 104, 106},
        {100, 50, 25, 13, 7},
        {100, 50, 25, 13, 7},
        {10000, 2500, 625, 169, 49},
        {0, 10000, 12500, 13125, 13294}
    };

    char* wsb = (char*)d_ws;
    const size_t AS = 6832128;                 // act buffer stride (bytes)
    u16* A = (u16*)(wsb + 0 * AS);
    u16* B = (u16*)(wsb + 1 * AS);
    u16* C = (u16*)(wsb + 2 * AS);
    u16* D = (u16*)(wsb + 3 * AS);
    u16* PC = (u16*)(wsb + 4 * AS);            // packed cls weights (<=3.84MB)
    u16* PR = (u16*)(wsb + 4 * AS + 3833856);  // packed reg weights (<=1.18MB)
    float* RAW = (float*)B;                    // reg raw out, reuses B

    // 1) feats -> bf16 channel-last into A
    for (int l = 0; l < 5; ++l) {
        int HW = TAB.HW[l];
        conv2bf<<<(HW + 63) / 64, 256, 0, stream>>>(feats[l], A, HW, TAB.GP0[l]);
    }

    // 2) tower stages, both heads fused
    const u16* cin[4]  = {A, B, D, B};
    u16*       cout_[4] = {B, D, B, D};
    const u16* rin[4]  = {A, C, A, C};
    u16*       rout[4] = {C, A, C, A};

    dim3 gtow(NPB, 2, 2);
    for (int s = 0; s < 4; ++s) {
        pack_w<<<(72 * 16 * 64 + 255) / 256, 256, 0, stream>>>(cls_tw + s * TW_STRIDE, PC, 256, 16);
        pack_w<<<(72 * 16 * 64 + 255) / 256, 256, 0, stream>>>(reg_tw + s * TW_STRIDE, PR, 256, 16);
        conv_tower<<<gtow, 256, 0, stream>>>(cin[s], cout_[s], rin[s], rout[s],
                                             PC, PR, cls_tb + s * 256, reg_tb + s * 256, TAB);
    }

    // 3) cls output conv (act in D)
    pack_w<<<(72 * 52 * 64 + 255) / 256, 256, 0, stream>>>(cls_ow, PC, 819, 52);
    conv_out_cls<<<dim3(NPB, 7, 1), 256, 0, stream>>>(D, PC, cls_ob, out, TAB);

    // 4) reg output conv (act in A) -> RAW (in B)
    pack_w<<<(72 * 3 * 64 + 255) / 256, 256, 0, stream>>>(reg_ow, PR, 36, 3);
    conv_out_reg<<<dim3(NPB, 1, 1), 256, 0, stream>>>(A, PR, reg_ob, RAW, TAB);

    // 5) decode boxes
    decode_boxes<<<(13343 * 9 + 255) / 256, 256, 0, stream>>>(RAW, out, TAB);
}

// Round 3
// 522.078 us; speedup vs baseline: 20.5061x; 1.3121x over previous
//
#include <hip/hip_runtime.h>
#include <math.h>

typedef unsigned short u16;
typedef __attribute__((ext_vector_type(8))) short s8v;   // 8 x bf16 (4 VGPRs)
typedef __attribute__((ext_vector_type(4))) float f4v;   // MFMA accumulator

#define NUM_CLASSES 91
#define NUM_ANCHORS 9
#define NT 130             // total 16x8 spatial tiles across 5 levels
#define TW_STRIDE (256*256*9)

struct Tab {
    int tstart[5];  // first tile index per level
    int tw[5];      // tiles along W
    int H[5], W[5], GP0[5];
};

__device__ __forceinline__ u16 f2bf(float f) {
    unsigned u = __float_as_uint(f);
    u += 0x7fffu + ((u >> 16) & 1u);
    return (u16)(u >> 16);
}

// ---------------------------------------------------------------------------
// fp32 NCHW -> bf16 [pixel][256] (channel-last), per level
// ---------------------------------------------------------------------------
__global__ __launch_bounds__(256) void conv2bf(const float* __restrict__ x,
                                               u16* __restrict__ out,
                                               int HW, int gp0)
{
    int p = blockIdx.x * 64 + (threadIdx.x & 63);
    int cg = threadIdx.x >> 6;              // 0..3
    if (p >= HW) return;
    #pragma unroll
    for (int pass = 0; pass < 8; ++pass) {
        int c0 = pass * 32 + cg * 8;
        s8v v8;
        #pragma unroll
        for (int j = 0; j < 8; ++j)
            v8[j] = (short)f2bf(x[(c0 + j) * HW + p]);
        *(s8v*)(out + (((gp0 + p) << 8) + c0)) = v8;
    }
}

// ---------------------------------------------------------------------------
// Pack conv weights [C_out][256][3][3] fp32 -> bf16 MFMA B-fragment order
// ---------------------------------------------------------------------------
__global__ __launch_bounds__(256) void pack_w(const float* __restrict__ w,
                                              u16* __restrict__ dst,
                                              int c_out_real, int nco16)
{
    int idx = blockIdx.x * 256 + threadIdx.x;
    int total = 72 * nco16 * 64;
    if (idx >= total) return;
    int lane = idx & 63;
    int t2 = idx >> 6;
    int co16 = t2 % nco16;
    int chunk = t2 / nco16;
    int tap = chunk >> 3, cib = chunk & 7;
    int co = co16 * 16 + (lane & 15);
    int ci0 = cib * 32 + ((lane >> 4) << 3);
    s8v v8;
    #pragma unroll
    for (int j = 0; j < 8; ++j) {
        float v = (co < c_out_real) ? w[((co << 8) + ci0 + j) * 9 + tap] : 0.f;
        v8[j] = (short)f2bf(v);
    }
    *(s8v*)(dst + (size_t)idx * 8) = v8;
}

// ---------------------------------------------------------------------------
// LDS-staged implicit-GEMM conv. Block: 256 thr = 4 waves (2 px-halves x
// 2 co-groups). Spatial tile 16w x 8h; halo 18x10 staged per 32-ci chunk.
// MODE: 0 = tower (relu, bf16 ch-last store, dual-head via blockIdx.z)
//       1 = cls out (sigmoid + scatter to d_out)
//       2 = reg out (raw fp32 [pixel][48])
// ---------------------------------------------------------------------------
template<int MODE>
__global__ __launch_bounds__(256) void conv_lds(
    const u16* __restrict__ actC, u16* __restrict__ outC,
    const u16* __restrict__ actR, u16* __restrict__ outR,
    const u16* __restrict__ wC, const u16* __restrict__ wR,
    const float* __restrict__ bC, const float* __restrict__ bR,
    float* __restrict__ fout, int nco16, Tab tab)
{
    __shared__ u16 lds[180 * 40];   // 14.4 KB: [halo px][40 u16 (32 ci + pad)]

    const int bx = blockIdx.x;
    int lvl = 0;
    if (bx >= tab.tstart[1]) lvl = 1;
    if (bx >= tab.tstart[2]) lvl = 2;
    if (bx >= tab.tstart[3]) lvl = 3;
    if (bx >= tab.tstart[4]) lvl = 4;
    const int H = tab.H[lvl], W = tab.W[lvl], gp0 = tab.GP0[lvl];
    const int t = bx - tab.tstart[lvl];
    const int tw = tab.tw[lvl];
    const int w0 = (t % tw) * 16;
    const int h0 = (t / tw) * 8;

    const int head = (MODE == 0) ? blockIdx.z : 0;
    const u16* act = head ? actR : actC;
    const u16* wpk = head ? wR : wC;
    const float* bias = head ? bR : bC;

    const int tid = threadIdx.x;
    const int lane = tid & 63, wv = tid >> 6;
    const int wv1 = wv & 1;                       // h-half: rows 0-3 / 4-7
    const int co16b = blockIdx.y * 8 + (wv >> 1) * 4;
    const int kgrp8 = (lane >> 4) << 3;           // ci sub-offset (u16)

    // precompute staging slots (720 16B-lane-loads, <=3 per thread)
    int sofs[3], slds[3];
    bool svalid[3], slive[3];
    #pragma unroll
    for (int i = 0; i < 3; ++i) {
        int k = tid + i * 256;
        slive[i] = k < 720;
        int kk = slive[i] ? k : 0;
        int px = kk >> 2, part = kk & 3;
        int hh = px / 18, ww = px % 18;
        int gh = h0 + hh - 1, gw = w0 + ww - 1;
        svalid[i] = ((unsigned)gh < (unsigned)H) && ((unsigned)gw < (unsigned)W);
        sofs[i] = ((gp0 + gh * W + gw) << 8) + part * 8;
        slds[i] = px * 40 + part * 8;
    }

    f4v acc[4][4];
    #pragma unroll
    for (int s = 0; s < 4; ++s)
        #pragma unroll
        for (int n = 0; n < 4; ++n)
            acc[s][n] = (f4v){0.f, 0.f, 0.f, 0.f};

    for (int cib = 0; cib < 8; ++cib) {
        // ---- stage halo tile for this 32-ci chunk ----
        #pragma unroll
        for (int i = 0; i < 3; ++i) {
            if (slive[i]) {
                s8v v = {};
                if (svalid[i]) v = *(const s8v*)(act + sofs[i] + cib * 32);
                *(s8v*)(&lds[slds[i]]) = v;
            }
        }
        __syncthreads();
        // ---- 9 taps: pure ds_read + global-B + MFMA ----
        #pragma unroll
        for (int tap = 0; tap < 9; ++tap) {
            const int dy = tap / 3 - 1, dx = tap % 3 - 1;
            const int chunk = tap * 8 + cib;
            s8v b[4];
            #pragma unroll
            for (int n = 0; n < 4; ++n) {
                int c16 = co16b + n;
                if (c16 >= nco16) c16 = nco16 - 1;
                b[n] = *(const s8v*)(wpk + (((size_t)(chunk * nco16 + c16)) << 9)
                                         + (lane << 3));
            }
            s8v a[4];
            #pragma unroll
            for (int s = 0; s < 4; ++s) {
                int hh = wv1 * 4 + s + dy + 1;
                int ww = (lane & 15) + dx + 1;
                a[s] = *(const s8v*)(&lds[(hh * 18 + ww) * 40 + kgrp8]);
            }
            #pragma unroll
            for (int s = 0; s < 4; ++s)
                #pragma unroll
                for (int n = 0; n < 4; ++n)
                    acc[s][n] = __builtin_amdgcn_mfma_f32_16x16x32_bf16(
                        a[s], b[n], acc[s][n], 0, 0, 0);
        }
        __syncthreads();
    }

    // ---- epilogue ----
    u16* outw = head ? outR : outC;
    #pragma unroll
    for (int n = 0; n < 4; ++n) {
        const int co = (co16b + n) * 16 + (lane & 15);
        #pragma unroll
        for (int s = 0; s < 4; ++s) {
            const int h = h0 + wv1 * 4 + s;
            #pragma unroll
            for (int j = 0; j < 4; ++j) {
                const int w = w0 + ((lane >> 4) << 2) + j;
                if (h < H && w < W) {
                    const int p = h * W + w;
                    if (MODE == 0) {
                        float v = acc[s][n][j] + bias[co];
                        outw[((gp0 + p) << 8) + co] = f2bf(fmaxf(v, 0.f));
                    } else if (MODE == 1) {
                        if (co < NUM_ANCHORS * NUM_CLASSES) {
                            float v = acc[s][n][j] + bias[co];
                            int a = co / NUM_CLASSES;
                            int k = co - a * NUM_CLASSES;
                            float sg = 1.f / (1.f + __expf(-v));
                            fout[((size_t)(gp0 + p) * 9 + a) * 95 + k] = sg;
                        }
                    } else {
                        if (co < 36)
                            fout[(gp0 + p) * 48 + co] = acc[s][n][j] + bias[co];
                    }
                }
            }
        }
    }
}

// ---------------------------------------------------------------------------
// box decode from raw [pixel][48]
// ---------------------------------------------------------------------------
__global__ __launch_bounds__(256) void decode_boxes(
    const float* __restrict__ raw, float* __restrict__ out, Tab tab)
{
    int idx = blockIdx.x * 256 + threadIdx.x;
    if (idx >= 13343 * 9) return;
    int gp = idx / 9, a = idx % 9;
    int lvl = 0;
    if (gp >= tab.GP0[1]) lvl = 1;
    if (gp >= tab.GP0[2]) lvl = 2;
    if (gp >= tab.GP0[3]) lvl = 3;
    if (gp >= tab.GP0[4]) lvl = 4;
    int p = gp - tab.GP0[lvl];
    int W = tab.W[lvl];
    int h = p / W, wc = p % W;
    float stride = (float)(8 << lvl);
    float base = (float)(32 << lvl);

    float dx = raw[gp * 48 + a * 4 + 0];
    float dy = raw[gp * 48 + a * 4 + 1];
    float dw = raw[gp * 48 + a * 4 + 2];
    float dh = raw[gp * 48 + a * 4 + 3];

    const float scales[3] = {1.f, 1.2599210498948732f, 1.5874010519681994f};
    const float hr[3] = {0.70710678118654752f, 1.f, 1.41421356237309505f};
    int ri = a / 3, si = a % 3;
    float sz = base * scales[si];
    float ah = hr[ri] * sz;
    float aw = sz / hr[ri];
    float acx = (float)wc * stride;
    float acy = (float)h * stride;

    const float CLAMP = 4.135166556742356f;
    dw = fminf(dw, CLAMP);
    dh = fminf(dh, CLAMP);
    float pcx = dx * aw + acx;
    float pcy = dy * ah + acy;
    float pw = expf(dw) * aw;
    float ph = expf(dh) * ah;

    float* o = out + ((size_t)gp * 9 + a) * 95 + 91;
    o[0] = pcx - 0.5f * pw;
    o[1] = pcy - 0.5f * ph;
    o[2] = pcx + 0.5f * pw;
    o[3] = pcy + 0.5f * ph;
}

// ---------------------------------------------------------------------------
extern "C" void kernel_launch(void* const* d_in, const int* in_sizes, int n_in,
                              void* d_out, int out_size, void* d_ws, size_t ws_size,
                              hipStream_t stream)
{
    const float* feats[5];
    for (int i = 0; i < 5; ++i) feats[i] = (const float*)d_in[i];
    const float* cls_tw = (const float*)d_in[5];
    const float* cls_tb = (const float*)d_in[6];
    const float* cls_ow = (const float*)d_in[7];
    const float* cls_ob = (const float*)d_in[8];
    const float* reg_tw = (const float*)d_in[9];
    const float* reg_tb = (const float*)d_in[10];
    const float* reg_ow = (const float*)d_in[11];
    const float* reg_ob = (const float*)d_in[12];
    float* out = (float*)d_out;

    static const Tab TAB = {
        {0, 91, 119, 127, 129},
        {7, 4, 2, 1, 1},
        {100, 50, 25, 13, 7},
        {100, 50, 25, 13, 7},
        {0, 10000, 12500, 13125, 13294}
    };
    static const int HWs[5] = {10000, 2500, 625, 169, 49};

    char* wsb = (char*)d_ws;
    const size_t AS = 6832128;                 // act buffer stride (bytes)
    u16* A = (u16*)(wsb + 0 * AS);
    u16* B = (u16*)(wsb + 1 * AS);
    u16* C = (u16*)(wsb + 2 * AS);
    u16* D = (u16*)(wsb + 3 * AS);
    u16* PC = (u16*)(wsb + 4 * AS);            // packed cls weights (<=3.84MB)
    u16* PR = (u16*)(wsb + 4 * AS + 3833856);  // packed reg weights (<=1.18MB)
    float* RAW = (float*)B;                    // reg raw out, reuses B

    // 1) feats -> bf16 channel-last into A
    for (int l = 0; l < 5; ++l)
        conv2bf<<<(HWs[l] + 63) / 64, 256, 0, stream>>>(feats[l], A, HWs[l], TAB.GP0[l]);

    // 2) tower stages, both heads fused
    const u16* cin[4]   = {A, B, D, B};
    u16*       cout_[4] = {B, D, B, D};
    const u16* rin[4]   = {A, C, A, C};
    u16*       rout[4]  = {C, A, C, A};

    for (int s = 0; s < 4; ++s) {
        pack_w<<<(72 * 16 * 64 + 255) / 256, 256, 0, stream>>>(cls_tw + s * TW_STRIDE, PC, 256, 16);
        pack_w<<<(72 * 16 * 64 + 255) / 256, 256, 0, stream>>>(reg_tw + s * TW_STRIDE, PR, 256, 16);
        conv_lds<0><<<dim3(NT, 2, 2), 256, 0, stream>>>(
            cin[s], cout_[s], rin[s], rout[s], PC, PR,
            cls_tb + s * 256, reg_tb + s * 256, nullptr, 16, TAB);
    }

    // 3) cls output conv (act in D)
    pack_w<<<(72 * 52 * 64 + 255) / 256, 256, 0, stream>>>(cls_ow, PC, 819, 52);
    conv_lds<1><<<dim3(NT, 7, 1), 256, 0, stream>>>(
        D, nullptr, nullptr, nullptr, PC, nullptr, cls_ob, nullptr, out, 52, TAB);

    // 4) reg output conv (act in A) -> RAW (in B)
    pack_w<<<(72 * 3 * 64 + 255) / 256, 256, 0, stream>>>(reg_ow, PR, 36, 3);
    conv_lds<2><<<dim3(NT, 1, 1), 256, 0, stream>>>(
        A, nullptr, nullptr, nullptr, PR, nullptr, reg_ob, nullptr, RAW, 3, TAB);

    // 5) decode boxes
    decode_boxes<<<(13343 * 9 + 255) / 256, 256, 0, stream>>>(RAW, out, TAB);
}